// Round 4
// baseline (51.768 us; speedup 1.0000x reference)
//
#include <hip/hip_runtime.h>
#include <hip/hip_bf16.h>
#include <math.h>

#define NA 4096
#define NM 64
#define NQ 64
#define NH 64

// ws layout (floats):
//   PARTT = ws            [10*NA]  transposed partials: slot*NA + n; slots 0..8 = pm[a*3+c], 9 = fpv
//   DQ    = ws + 10*NA    [64*NA]  de_dq per atom
//   WDR   = ws + 74*NA    [256*NA] (-nmask^2 * dr) per (atom, m), stride-4
#define WS_FLOATS (330 * NA)

// ---------------- Kernel 1: per-atom MLP chain (256 thr / atom) ----------------
__global__ __launch_bounds__(256) void tnep_prep(
    const float* __restrict__ desc,
    const int*   __restrict__ gidx,
    const float* __restrict__ pos,
    const int*   __restrict__ Zp,
    const float* __restrict__ box,
    const float* __restrict__ amaskp,
    const float* __restrict__ nmaskp,
    const float* __restrict__ W0,
    const float* __restrict__ b0,
    const float* __restrict__ W1,
    const float* __restrict__ W0p,
    const float* __restrict__ b0p,
    const float* __restrict__ W1p,
    const float* __restrict__ b1p,
    float* __restrict__ ws)
{
    const int n    = blockIdx.x;
    const int tid  = threadIdx.x;
    const int w    = tid >> 6;
    const int lane = tid & 63;
    const int z    = Zp[n];

    float* PARTT = ws;
    float* DQ    = ws + 10 * NA;
    float* WDR   = ws + 74 * NA;

    __shared__ float sW0[NQ * 65];   // padded: fwd (row bcast) & bwd (col) conflict-free
    __shared__ float sdesc[NQ];
    __shared__ float sde_da[NH];

    // Cooperative stage of W0[z] (16 KB), all 256 threads.
    const float4* W0v = reinterpret_cast<const float4*>(W0 + (size_t)z * NQ * NH);
#pragma unroll
    for (int i = 0; i < 4; ++i) {
        int f = i * 256 + tid;
        float4 v = W0v[f];
        int q  = f >> 4;
        int h0 = (f & 15) * 4;
        float* p = &sW0[q * 65 + h0];
        p[0] = v.x; p[1] = v.y; p[2] = v.z; p[3] = v.w;
    }
    if (w == 0) sdesc[lane] = desc[n * NQ + lane];
    if (w == 1) {
        // Minimal-image displacement scalars, -nmask^2 folded in (lane = m).
        int g = gidx[n * NM + lane];
        float Lx = box[0], Ly = box[4], Lz = box[8];
        float dx = pos[g * 3 + 0] - pos[n * 3 + 0];
        float dy = pos[g * 3 + 1] - pos[n * 3 + 1];
        float dz = pos[g * 3 + 2] - pos[n * 3 + 2];
        dx -= Lx * rintf(dx * (1.0f / Lx));   // rintf = round-half-even = jnp.round
        dy -= Ly * rintf(dy * (1.0f / Ly));
        dz -= Lz * rintf(dz * (1.0f / Lz));
        float nm = nmaskp[n * NM + lane];
        float wt = -nm * nm;
        float4 wd = make_float4(wt * dx, wt * dy, wt * dz, 0.0f);
        *reinterpret_cast<float4*>(WDR + (size_t)n * 256 + lane * 4) = wd;
    }
    __syncthreads();   // sW0, sdesc ready

    if (w == 0) {
        // Tensor ANN forward (lane = h).
        float amask = amaskp[n];
        float a_t = b0[z * NH + lane];
#pragma unroll 8
        for (int q = 0; q < NQ; ++q)
            a_t = fmaf(sdesc[q], sW0[q * 65 + lane], a_t);
        float hT = tanhf(a_t) * amask;
        sde_da[lane] = (1.0f - hT * hT) * W1[z * NH + lane];
    } else if (w == 2) {
        // Pol ANN (independent of LDS; W0p/desc are L2-resident).
        float amask = amaskp[n];
        float a_p = b0p[z * NH + lane];
        const float* W0prow = W0p + (size_t)z * NQ * NH;
        const float* drow   = desc + (size_t)n * NQ;
#pragma unroll 8
        for (int q = 0; q < NQ; ++q)
            a_p = fmaf(drow[q], W0prow[q * NH + lane], a_p);
        float hP = tanhf(a_p) * amask;
        float fp = hP * W1p[z * NH + lane];
#pragma unroll
        for (int s = 1; s < 64; s <<= 1) fp += __shfl_xor(fp, s, 64);
        if (lane == 0) PARTT[9 * NA + n] = (fp + b1p[0]) * amask;
    }
    __syncthreads();   // sde_da ready

    if (w == 0) {
        // Backward: de_dq[q] = sum_h de_da[h] * W0[q][h]  (lane = q).
        float dq = 0.0f;
#pragma unroll 8
        for (int h = 0; h < NH; ++h)
            dq = fmaf(sde_da[h], sW0[lane * 65 + h], dq);
        DQ[(size_t)n * 64 + lane] = dq;
    }
}

// ------------- Kernel 2: pure gradient streamer (tiny LDS, lean VGPR) -------------
__global__ __launch_bounds__(256, 8) void tnep_stream(
    const float* __restrict__ grad,
    float* __restrict__ ws)
{
    const int n    = blockIdx.x;
    const int tid  = threadIdx.x;
    const int w    = tid >> 6;
    const int lane = tid & 63;

    float* PARTT = ws;
    const float* DQ  = ws + 10 * NA;
    const float* WDR = ws + 74 * NA;

    __shared__ float swdr[NM * 4];
    __shared__ float sacc[4][12];

    swdr[tid] = WDR[(size_t)n * 256 + tid];
    float4 dq4 = *reinterpret_cast<const float4*>(DQ + (size_t)n * 64 + 4 * (lane & 15));
    __syncthreads();

    // Wave w owns m in [w*16, w*16+16); lane = msub*16 + q4.
    // Per-lane partials over its q-slice; single cross-lane reduce at the end.
    const int msub = lane >> 4;
    const int q4   = lane & 15;
    float acc[3][3] = {{0.f,0.f,0.f},{0.f,0.f,0.f},{0.f,0.f,0.f}};

    const int m0 = w * 16;
    const float4* gbase = reinterpret_cast<const float4*>(grad)
                          + ((size_t)n * NM + m0) * 48 + msub * 48 + q4;
#pragma unroll
    for (int gset = 0; gset < 4; ++gset) {
        const float4* gp = gbase + gset * 192;
        const int m = m0 + gset * 4 + msub;
        float4 wd = *reinterpret_cast<const float4*>(&swdr[m * 4]);
#pragma unroll
        for (int c = 0; c < 3; ++c) {
            float4 g4 = gp[c * 16];
            float s = fmaf(dq4.x, g4.x, fmaf(dq4.y, g4.y,
                      fmaf(dq4.z, g4.z, dq4.w * g4.w)));
            acc[0][c] = fmaf(s, wd.x, acc[0][c]);
            acc[1][c] = fmaf(s, wd.y, acc[1][c]);
            acc[2][c] = fmaf(s, wd.z, acc[2][c]);
        }
    }

    // One 64-lane reduction per wave, then cross-wave via LDS.
#pragma unroll
    for (int a = 0; a < 3; ++a)
#pragma unroll
        for (int c = 0; c < 3; ++c) {
            float v = acc[a][c];
#pragma unroll
            for (int s = 1; s < 64; s <<= 1) v += __shfl_xor(v, s, 64);
            if (lane == 0) sacc[w][a * 3 + c] = v;
        }
    __syncthreads();
    if (tid < 9)
        PARTT[tid * NA + n] = sacc[0][tid] + sacc[1][tid] + sacc[2][tid] + sacc[3][tid];
}

// ---------------- Final reduction: 10 waves, one slot each, coalesced ----------------
__global__ __launch_bounds__(640) void tnep_reduce(const float* __restrict__ ws,
                                                   float* __restrict__ out)
{
    __shared__ float sred[10];
    const int w    = threadIdx.x >> 6;
    const int lane = threadIdx.x & 63;

    const float4* p = reinterpret_cast<const float4*>(ws + (size_t)w * NA);
    float s = 0.f;
#pragma unroll
    for (int i = 0; i < 16; ++i) {
        float4 v = p[lane + 64 * i];
        s += (v.x + v.y) + (v.z + v.w);
    }
#pragma unroll
    for (int t = 1; t < 64; t <<= 1) s += __shfl_xor(s, t, 64);
    if (lane == 0) sred[w] = s;
    __syncthreads();
    if (threadIdx.x == 0) {
        float S = sred[9];
        out[0] = sred[0] + S;   // pm00 + scalar
        out[1] = sred[4] + S;   // pm11 + scalar
        out[2] = sred[8] + S;   // pm22 + scalar
        out[3] = sred[1];       // pm01
        out[4] = sred[5];       // pm12
        out[5] = sred[6];       // pm20
    }
}

// ---------------- Fallback (tiny ws): monolithic with atomics ----------------
__global__ __launch_bounds__(64) void tnep_mono(
    const float* __restrict__ desc,
    const float* __restrict__ grad,
    const int*   __restrict__ gidx,
    const float* __restrict__ pos,
    const int*   __restrict__ Zp,
    const float* __restrict__ box,
    const float* __restrict__ amaskp,
    const float* __restrict__ nmaskp,
    const float* __restrict__ W0,
    const float* __restrict__ b0,
    const float* __restrict__ W1,
    const float* __restrict__ W0p,
    const float* __restrict__ b0p,
    const float* __restrict__ W1p,
    const float* __restrict__ b1p,
    float* __restrict__ out)
{
    const int n    = blockIdx.x;
    const int lane = threadIdx.x;
    const int z    = Zp[n];
    const float amask = amaskp[n];

    __shared__ float sdesc[NQ];
    __shared__ float sW0[NQ * 65];
    __shared__ float sde_da[NH];
    __shared__ float sde_dq[NQ];
    __shared__ float sdr[NM * 4];

    sdesc[lane] = desc[n * NQ + lane];
    const float4* W0v = reinterpret_cast<const float4*>(W0 + (size_t)z * NQ * NH);
#pragma unroll
    for (int i = 0; i < 16; ++i) {
        float4 v = W0v[i * 64 + lane];
        int q  = 4 * i + (lane >> 4);
        int h0 = 4 * (lane & 15);
        float* p = &sW0[q * 65 + h0];
        p[0] = v.x; p[1] = v.y; p[2] = v.z; p[3] = v.w;
    }
    {
        int g = gidx[n * NM + lane];
        float Lx = box[0], Ly = box[4], Lz = box[8];
        float dx = pos[g * 3 + 0] - pos[n * 3 + 0];
        float dy = pos[g * 3 + 1] - pos[n * 3 + 1];
        float dz = pos[g * 3 + 2] - pos[n * 3 + 2];
        dx -= Lx * rintf(dx * (1.0f / Lx));
        dy -= Ly * rintf(dy * (1.0f / Ly));
        dz -= Lz * rintf(dz * (1.0f / Lz));
        float nm = nmaskp[n * NM + lane];
        float wt = -nm * nm;
        sdr[lane * 4 + 0] = wt * dx;
        sdr[lane * 4 + 1] = wt * dy;
        sdr[lane * 4 + 2] = wt * dz;
        sdr[lane * 4 + 3] = 0.0f;
    }
    __syncthreads();

    float a_t = b0 [z * NH + lane];
    float a_p = b0p[z * NH + lane];
    const float* W0prow = W0p + (size_t)z * NQ * NH;
#pragma unroll 8
    for (int q = 0; q < NQ; ++q) {
        float d = sdesc[q];
        a_t = fmaf(d, sW0[q * 65 + lane], a_t);
        a_p = fmaf(d, W0prow[q * NH + lane], a_p);
    }
    float hT = tanhf(a_t) * amask;
    float hP = tanhf(a_p) * amask;
    sde_da[lane] = (1.0f - hT * hT) * W1[z * NH + lane];
    float fp = hP * W1p[z * NH + lane];
#pragma unroll
    for (int s = 1; s < 64; s <<= 1) fp += __shfl_xor(fp, s, 64);
    __syncthreads();

    float dq = 0.0f;
#pragma unroll 8
    for (int h = 0; h < NH; ++h)
        dq = fmaf(sde_da[h], sW0[lane * 65 + h], dq);
    sde_dq[lane] = dq;
    __syncthreads();

    const int msub = lane >> 4;
    const int q4   = lane & 15;
    float4 dq4 = *reinterpret_cast<const float4*>(&sde_dq[4 * q4]);
    float acc[3][3] = {{0.f,0.f,0.f},{0.f,0.f,0.f},{0.f,0.f,0.f}};
    const float4* gbase = reinterpret_cast<const float4*>(grad)
                          + (size_t)n * NM * 48 + msub * 48 + q4;
#pragma unroll
    for (int gset = 0; gset < 16; ++gset) {
        const float4* gp = gbase + gset * 192;
        const int m = gset * 4 + msub;
        float wd0 = sdr[m * 4 + 0];
        float wd1 = sdr[m * 4 + 1];
        float wd2 = sdr[m * 4 + 2];
#pragma unroll
        for (int c = 0; c < 3; ++c) {
            float4 g4 = gp[c * 16];
            float s = fmaf(dq4.x, g4.x, fmaf(dq4.y, g4.y, fmaf(dq4.z, g4.z, dq4.w * g4.w)));
            acc[0][c] = fmaf(s, wd0, acc[0][c]);
            acc[1][c] = fmaf(s, wd1, acc[1][c]);
            acc[2][c] = fmaf(s, wd2, acc[2][c]);
        }
    }
    float fpv = (fp + b1p[0]) * amask;
#pragma unroll
    for (int a = 0; a < 3; ++a)
#pragma unroll
        for (int c = 0; c < 3; ++c) {
            float v = acc[a][c];
#pragma unroll
            for (int s = 1; s < 64; s <<= 1) v += __shfl_xor(v, s, 64);
            acc[a][c] = v;
        }
    if (lane == 0) {
        atomicAdd(out + 0, acc[0][0] + fpv);
        atomicAdd(out + 1, acc[1][1] + fpv);
        atomicAdd(out + 2, acc[2][2] + fpv);
        atomicAdd(out + 3, acc[0][1]);
        atomicAdd(out + 4, acc[1][2]);
        atomicAdd(out + 5, acc[2][0]);
    }
}

__global__ void tnep_zero(float* out)
{
    if (threadIdx.x < 6) out[threadIdx.x] = 0.f;
}

extern "C" void kernel_launch(void* const* d_in, const int* in_sizes, int n_in,
                              void* d_out, int out_size, void* d_ws, size_t ws_size,
                              hipStream_t stream)
{
    const float* desc  = (const float*)d_in[0];
    const float* grad  = (const float*)d_in[1];
    const int*   gidx  = (const int*)  d_in[2];
    const float* pos   = (const float*)d_in[3];
    const int*   Zp    = (const int*)  d_in[4];
    const float* box   = (const float*)d_in[5];
    const float* amask = (const float*)d_in[6];
    const float* nmask = (const float*)d_in[7];
    const float* W0    = (const float*)d_in[8];
    const float* b0    = (const float*)d_in[9];
    const float* W1    = (const float*)d_in[10];
    // d_in[11] = b1 (unused by reference)
    const float* W0p   = (const float*)d_in[12];
    const float* b0p   = (const float*)d_in[13];
    const float* W1p   = (const float*)d_in[14];
    const float* b1p   = (const float*)d_in[15];
    float* out = (float*)d_out;
    float* ws  = (float*)d_ws;

    if (ws_size >= (size_t)WS_FLOATS * sizeof(float)) {
        tnep_prep<<<NA, 256, 0, stream>>>(desc, gidx, pos, Zp, box, amask, nmask,
                                          W0, b0, W1, W0p, b0p, W1p, b1p, ws);
        tnep_stream<<<NA, 256, 0, stream>>>(grad, ws);
        tnep_reduce<<<1, 640, 0, stream>>>(ws, out);
    } else {
        tnep_zero<<<1, 64, 0, stream>>>(out);
        tnep_mono<<<NA, 64, 0, stream>>>(desc, grad, gidx, pos, Zp, box, amask, nmask,
                                         W0, b0, W1, W0p, b0p, W1p, b1p, out);
    }
}

// Round 6
// 43.394 us; speedup vs baseline: 1.1930x; 1.1930x over previous
//
#include <hip/hip_runtime.h>
#include <hip/hip_bf16.h>
#include <math.h>

#define NA 4096
#define NM 64
#define NQ 64
#define NH 64

// ws layout (floats): PARTT[slot][NA]; slots 0..8 = pm[a*3+c], slot 9 = fpv.
#define WS_FLOATS (10 * NA)

// ---------------- Main fused kernel: one atom per 256-thread block ----------------
// Waves: 0 = tensor ANN fwd+bwd (wave-internal), 1 = displacement scalars,
// 2 = pol ANN; all 4 waves stream. 6/12 grad float4s per lane preloaded before
// the first barrier so HBM latency hides under the MLP preamble.
__global__ __launch_bounds__(256) void tnep_fused(
    const float* __restrict__ desc,
    const float* __restrict__ grad,
    const int*   __restrict__ gidx,
    const float* __restrict__ pos,
    const int*   __restrict__ Zp,
    const float* __restrict__ box,
    const float* __restrict__ amaskp,
    const float* __restrict__ nmaskp,
    const float* __restrict__ W0,
    const float* __restrict__ b0,
    const float* __restrict__ W1,
    const float* __restrict__ W0p,
    const float* __restrict__ b0p,
    const float* __restrict__ W1p,
    const float* __restrict__ b1p,
    float* __restrict__ ws)
{
    const int n    = blockIdx.x;
    const int tid  = threadIdx.x;
    const int w    = tid >> 6;
    const int lane = tid & 63;
    const int msub = lane >> 4;
    const int q4   = lane & 15;
    const int z    = Zp[n];

    float* PARTT = ws;

    __shared__ float sW0[NQ * 65];   // padded: fwd (stride-1) & bwd (stride-65) conflict-free
    __shared__ float sdesc[NQ];
    __shared__ float sde_da[NH];
    __shared__ float sde_dq[NQ];
    __shared__ float swdr[NM * 4];
    __shared__ float sacc[4][9];
    __shared__ float sfpv;

    // ---- Early preloads: 6 of this lane's 12 grad float4s, in flight across
    // the whole MLP preamble. ----
    const float4* gbase = reinterpret_cast<const float4*>(grad)
                          + ((size_t)n * NM + w * 16 + msub) * 48 + q4;
    float4 p00 = gbase[0],   p01 = gbase[16],  p02 = gbase[32];    // gset 0, c=0..2
    float4 p10 = gbase[192], p11 = gbase[208], p12 = gbase[224];   // gset 1, c=0..2

    // Cooperative stage of W0[z] (16 KB), all 256 threads.
    const float4* W0v = reinterpret_cast<const float4*>(W0 + (size_t)z * NQ * NH);
#pragma unroll
    for (int i = 0; i < 4; ++i) {
        int f = i * 256 + tid;
        float4 v = W0v[f];
        int q  = f >> 4;
        int h0 = (f & 15) * 4;
        float* p = &sW0[q * 65 + h0];
        p[0] = v.x; p[1] = v.y; p[2] = v.z; p[3] = v.w;
    }
    if (w == 0) sdesc[lane] = desc[n * NQ + lane];
    if (w == 1) {
        // Minimal-image displacement scalars, -nmask^2 folded in (lane = m).
        int g = gidx[n * NM + lane];
        float Lx = box[0], Ly = box[4], Lz = box[8];
        float dx = pos[g * 3 + 0] - pos[n * 3 + 0];
        float dy = pos[g * 3 + 1] - pos[n * 3 + 1];
        float dz = pos[g * 3 + 2] - pos[n * 3 + 2];
        dx -= Lx * rintf(dx * (1.0f / Lx));   // rintf = round-half-even = jnp.round
        dy -= Ly * rintf(dy * (1.0f / Ly));
        dz -= Lz * rintf(dz * (1.0f / Lz));
        float nm = nmaskp[n * NM + lane];
        float wt = -nm * nm;
        swdr[lane * 4 + 0] = wt * dx;
        swdr[lane * 4 + 1] = wt * dy;
        swdr[lane * 4 + 2] = wt * dz;
        swdr[lane * 4 + 3] = 0.0f;
    }
    __syncthreads();   // B1: sW0, sdesc, swdr ready

    if (w == 0) {
        // Tensor ANN fwd + bwd, entirely within wave 0 (wave-synchronous LDS;
        // DS ops are in-order within a wave, no barrier needed between phases).
        float amask = amaskp[n];
        float a_t = b0[z * NH + lane];
#pragma unroll 8
        for (int q = 0; q < NQ; ++q)
            a_t = fmaf(sdesc[q], sW0[q * 65 + lane], a_t);
        float hT = tanhf(a_t) * amask;
        sde_da[lane] = (1.0f - hT * hT) * W1[z * NH + lane];   // lane = h
        float dq = 0.0f;
#pragma unroll 8
        for (int h = 0; h < NH; ++h)                            // lane = q
            dq = fmaf(sde_da[h], sW0[lane * 65 + h], dq);
        sde_dq[lane] = dq;
    } else if (w == 2) {
        // Pol ANN (global reads only; W0p/desc are L2-resident).
        float amask = amaskp[n];
        float a_p = b0p[z * NH + lane];
        const float* W0prow = W0p + (size_t)z * NQ * NH;
        const float* drow   = desc + (size_t)n * NQ;
#pragma unroll 8
        for (int q = 0; q < NQ; ++q)
            a_p = fmaf(drow[q], W0prow[q * NH + lane], a_p);
        float hP = tanhf(a_p) * amask;
        float fp = hP * W1p[z * NH + lane];
#pragma unroll
        for (int s = 1; s < 64; s <<= 1) fp += __shfl_xor(fp, s, 64);
        if (lane == 0) sfpv = (fp + b1p[0]) * amask;
    }
    __syncthreads();   // B2: sde_dq, sfpv ready

    // ---- Streaming phase: wave w owns m in [w*16, w*16+16); lane = msub*16+q4.
    float4 dq4 = *reinterpret_cast<const float4*>(&sde_dq[4 * q4]);
    float acc[3][3] = {{0.f,0.f,0.f},{0.f,0.f,0.f},{0.f,0.f,0.f}};
    const int mb4 = (w * 16 + msub) * 4;

#define TNEP_DOT(g4) fmaf(dq4.x, (g4).x, fmaf(dq4.y, (g4).y, fmaf(dq4.z, (g4).z, dq4.w * (g4).w)))
#define TNEP_ACC(g0, g1, g2, widx)                                              \
    {                                                                           \
        float wd0 = swdr[(widx) + 0], wd1 = swdr[(widx) + 1], wd2 = swdr[(widx) + 2]; \
        float s0 = TNEP_DOT(g0), s1 = TNEP_DOT(g1), s2 = TNEP_DOT(g2);          \
        acc[0][0] = fmaf(s0, wd0, acc[0][0]);                                   \
        acc[1][0] = fmaf(s0, wd1, acc[1][0]);                                   \
        acc[2][0] = fmaf(s0, wd2, acc[2][0]);                                   \
        acc[0][1] = fmaf(s1, wd0, acc[0][1]);                                   \
        acc[1][1] = fmaf(s1, wd1, acc[1][1]);                                   \
        acc[2][1] = fmaf(s1, wd2, acc[2][1]);                                   \
        acc[0][2] = fmaf(s2, wd0, acc[0][2]);                                   \
        acc[1][2] = fmaf(s2, wd1, acc[1][2]);                                   \
        acc[2][2] = fmaf(s2, wd2, acc[2][2]);                                   \
    }

    TNEP_ACC(p00, p01, p02, mb4);            // gset 0 (preloaded)
    TNEP_ACC(p10, p11, p12, mb4 + 16);       // gset 1 (preloaded)
    {
        float4 g0 = gbase[384], g1 = gbase[400], g2 = gbase[416];   // gset 2
        TNEP_ACC(g0, g1, g2, mb4 + 32);
    }
    {
        float4 g0 = gbase[576], g1 = gbase[592], g2 = gbase[608];   // gset 3
        TNEP_ACC(g0, g1, g2, mb4 + 48);
    }
#undef TNEP_ACC
#undef TNEP_DOT

    // One 64-lane reduction per wave, then cross-wave via LDS.
#pragma unroll
    for (int a = 0; a < 3; ++a)
#pragma unroll
        for (int c = 0; c < 3; ++c) {
            float v = acc[a][c];
#pragma unroll
            for (int s = 1; s < 64; s <<= 1) v += __shfl_xor(v, s, 64);
            if (lane == 0) sacc[w][a * 3 + c] = v;
        }
    __syncthreads();   // B3: sacc, sfpv ready

    if (tid < 9)
        PARTT[(size_t)tid * NA + n] = sacc[0][tid] + sacc[1][tid] + sacc[2][tid] + sacc[3][tid];
    if (tid == 9)
        PARTT[(size_t)9 * NA + n] = sfpv;
}

// ---------------- Final reduction: 10 waves, one slot each, coalesced ----------------
__global__ __launch_bounds__(640) void tnep_reduce(const float* __restrict__ ws,
                                                   float* __restrict__ out)
{
    __shared__ float sred[10];
    const int w    = threadIdx.x >> 6;
    const int lane = threadIdx.x & 63;

    const float4* p = reinterpret_cast<const float4*>(ws + (size_t)w * NA);
    float s = 0.f;
#pragma unroll
    for (int i = 0; i < 16; ++i) {
        float4 v = p[lane + 64 * i];
        s += (v.x + v.y) + (v.z + v.w);
    }
#pragma unroll
    for (int t = 1; t < 64; t <<= 1) s += __shfl_xor(s, t, 64);
    if (lane == 0) sred[w] = s;
    __syncthreads();
    if (threadIdx.x == 0) {
        float S = sred[9];
        out[0] = sred[0] + S;   // pm00 + scalar
        out[1] = sred[4] + S;   // pm11 + scalar
        out[2] = sred[8] + S;   // pm22 + scalar
        out[3] = sred[1];       // pm01
        out[4] = sred[5];       // pm12
        out[5] = sred[6];       // pm20
    }
}

// ---------------- Fallback (tiny ws): monolithic with atomics ----------------
__global__ __launch_bounds__(64) void tnep_mono(
    const float* __restrict__ desc,
    const float* __restrict__ grad,
    const int*   __restrict__ gidx,
    const float* __restrict__ pos,
    const int*   __restrict__ Zp,
    const float* __restrict__ box,
    const float* __restrict__ amaskp,
    const float* __restrict__ nmaskp,
    const float* __restrict__ W0,
    const float* __restrict__ b0,
    const float* __restrict__ W1,
    const float* __restrict__ W0p,
    const float* __restrict__ b0p,
    const float* __restrict__ W1p,
    const float* __restrict__ b1p,
    float* __restrict__ out)
{
    const int n    = blockIdx.x;
    const int lane = threadIdx.x;
    const int z    = Zp[n];
    const float amask = amaskp[n];

    __shared__ float sdesc[NQ];
    __shared__ float sW0[NQ * 65];
    __shared__ float sde_da[NH];
    __shared__ float sde_dq[NQ];
    __shared__ float sdr[NM * 4];

    sdesc[lane] = desc[n * NQ + lane];
    const float4* W0v = reinterpret_cast<const float4*>(W0 + (size_t)z * NQ * NH);
#pragma unroll
    for (int i = 0; i < 16; ++i) {
        float4 v = W0v[i * 64 + lane];
        int q  = 4 * i + (lane >> 4);
        int h0 = 4 * (lane & 15);
        float* p = &sW0[q * 65 + h0];
        p[0] = v.x; p[1] = v.y; p[2] = v.z; p[3] = v.w;
    }
    {
        int g = gidx[n * NM + lane];
        float Lx = box[0], Ly = box[4], Lz = box[8];
        float dx = pos[g * 3 + 0] - pos[n * 3 + 0];
        float dy = pos[g * 3 + 1] - pos[n * 3 + 1];
        float dz = pos[g * 3 + 2] - pos[n * 3 + 2];
        dx -= Lx * rintf(dx * (1.0f / Lx));
        dy -= Ly * rintf(dy * (1.0f / Ly));
        dz -= Lz * rintf(dz * (1.0f / Lz));
        float nm = nmaskp[n * NM + lane];
        float wt = -nm * nm;
        sdr[lane * 4 + 0] = wt * dx;
        sdr[lane * 4 + 1] = wt * dy;
        sdr[lane * 4 + 2] = wt * dz;
        sdr[lane * 4 + 3] = 0.0f;
    }
    __syncthreads();

    float a_t = b0 [z * NH + lane];
    float a_p = b0p[z * NH + lane];
    const float* W0prow = W0p + (size_t)z * NQ * NH;
#pragma unroll 8
    for (int q = 0; q < NQ; ++q) {
        float d = sdesc[q];
        a_t = fmaf(d, sW0[q * 65 + lane], a_t);
        a_p = fmaf(d, W0prow[q * NH + lane], a_p);
    }
    float hT = tanhf(a_t) * amask;
    float hP = tanhf(a_p) * amask;
    sde_da[lane] = (1.0f - hT * hT) * W1[z * NH + lane];
    float fp = hP * W1p[z * NH + lane];
#pragma unroll
    for (int s = 1; s < 64; s <<= 1) fp += __shfl_xor(fp, s, 64);
    __syncthreads();

    float dq = 0.0f;
#pragma unroll 8
    for (int h = 0; h < NH; ++h)
        dq = fmaf(sde_da[h], sW0[lane * 65 + h], dq);
    sde_dq[lane] = dq;
    __syncthreads();

    const int msub = lane >> 4;
    const int q4   = lane & 15;
    float4 dq4 = *reinterpret_cast<const float4*>(&sde_dq[4 * q4]);
    float acc[3][3] = {{0.f,0.f,0.f},{0.f,0.f,0.f},{0.f,0.f,0.f}};
    const float4* gbase = reinterpret_cast<const float4*>(grad)
                          + (size_t)n * NM * 48 + msub * 48 + q4;
#pragma unroll
    for (int gset = 0; gset < 16; ++gset) {
        const float4* gp = gbase + gset * 192;
        const int m = gset * 4 + msub;
        float wd0 = sdr[m * 4 + 0];
        float wd1 = sdr[m * 4 + 1];
        float wd2 = sdr[m * 4 + 2];
#pragma unroll
        for (int c = 0; c < 3; ++c) {
            float4 g4 = gp[c * 16];
            float s = fmaf(dq4.x, g4.x, fmaf(dq4.y, g4.y, fmaf(dq4.z, g4.z, dq4.w * g4.w)));
            acc[0][c] = fmaf(s, wd0, acc[0][c]);
            acc[1][c] = fmaf(s, wd1, acc[1][c]);
            acc[2][c] = fmaf(s, wd2, acc[2][c]);
        }
    }
    float fpv = (fp + b1p[0]) * amask;
#pragma unroll
    for (int a = 0; a < 3; ++a)
#pragma unroll
        for (int c = 0; c < 3; ++c) {
            float v = acc[a][c];
#pragma unroll
            for (int s = 1; s < 64; s <<= 1) v += __shfl_xor(v, s, 64);
            acc[a][c] = v;
        }
    if (lane == 0) {
        atomicAdd(out + 0, acc[0][0] + fpv);
        atomicAdd(out + 1, acc[1][1] + fpv);
        atomicAdd(out + 2, acc[2][2] + fpv);
        atomicAdd(out + 3, acc[0][1]);
        atomicAdd(out + 4, acc[1][2]);
        atomicAdd(out + 5, acc[2][0]);
    }
}

__global__ void tnep_zero(float* out)
{
    if (threadIdx.x < 6) out[threadIdx.x] = 0.f;
}

extern "C" void kernel_launch(void* const* d_in, const int* in_sizes, int n_in,
                              void* d_out, int out_size, void* d_ws, size_t ws_size,
                              hipStream_t stream)
{
    const float* desc  = (const float*)d_in[0];
    const float* grad  = (const float*)d_in[1];
    const int*   gidx  = (const int*)  d_in[2];
    const float* pos   = (const float*)d_in[3];
    const int*   Zp    = (const int*)  d_in[4];
    const float* box   = (const float*)d_in[5];
    const float* amask = (const float*)d_in[6];
    const float* nmask = (const float*)d_in[7];
    const float* W0    = (const float*)d_in[8];
    const float* b0    = (const float*)d_in[9];
    const float* W1    = (const float*)d_in[10];
    // d_in[11] = b1 (unused by reference)
    const float* W0p   = (const float*)d_in[12];
    const float* b0p   = (const float*)d_in[13];
    const float* W1p   = (const float*)d_in[14];
    const float* b1p   = (const float*)d_in[15];
    float* out = (float*)d_out;
    float* ws  = (float*)d_ws;

    if (ws_size >= (size_t)WS_FLOATS * sizeof(float)) {
        tnep_fused<<<NA, 256, 0, stream>>>(desc, grad, gidx, pos, Zp, box, amask, nmask,
                                           W0, b0, W1, W0p, b0p, W1p, b1p, ws);
        tnep_reduce<<<1, 640, 0, stream>>>(ws, out);
    } else {
        tnep_zero<<<1, 64, 0, stream>>>(out);
        tnep_mono<<<NA, 64, 0, stream>>>(desc, grad, gidx, pos, Zp, box, amask, nmask,
                                         W0, b0, W1, W0p, b0p, W1p, b1p, out);
    }
}